// Round 6
// baseline (157.021 us; speedup 1.0000x reference)
//
#include <hip/hip_runtime.h>
#include <math.h>

#define D_MODEL 512
#define NHEAD   8
#define HD      64
#define T_SEQ   2048
#define BATCH   4
#define M_ROWS  (BATCH * T_SEQ)   // 8192

typedef __attribute__((ext_vector_type(8))) short        short8;   // 8 bf16
typedef __attribute__((ext_vector_type(4))) float        floatx4;
typedef __attribute__((ext_vector_type(4))) unsigned int uintx4;

// round-to-nearest-even fp32 -> bf16 (bit math; inputs finite)
__device__ __forceinline__ unsigned short f2bf(float f) {
    unsigned int u = __float_as_uint(f);
    unsigned int r = u + 0x7FFFu + ((u >> 16) & 1u);
    return (unsigned short)(r >> 16);
}

__device__ __forceinline__ float bf2f(unsigned short u) {
    return __uint_as_float((unsigned int)u << 16);
}

// raw v_exp_f32: D = 2^S0 (base-2 exponential, no hidden *log2e multiply)
__device__ __forceinline__ float exp2_raw(float x) {
    float r;
    asm("v_exp_f32 %0, %1" : "=v"(r) : "v"(x));
    return r;
}

// pack 8 fp32 -> 8 bf16 in an int4
__device__ __forceinline__ int4 cvt8(float4 a, float4 b) {
    union { unsigned short u[8]; int4 v; } r;
    r.u[0] = f2bf(a.x); r.u[1] = f2bf(a.y); r.u[2] = f2bf(a.z); r.u[3] = f2bf(a.w);
    r.u[4] = f2bf(b.x); r.u[5] = f2bf(b.y); r.u[6] = f2bf(b.z); r.u[7] = f2bf(b.w);
    return r.v;
}

// async global->LDS, 16 B per lane; LDS dest = base + lane*16 (wave-uniform base)
__device__ __forceinline__ void gload16(const void* g, void* l) {
    __builtin_amdgcn_global_load_lds(
        (const __attribute__((address_space(1))) void*)g,
        (__attribute__((address_space(3))) void*)l, 16, 0, 0);
}

// decompose tile-slot t for head period P: residue r, q-tile mt, subseq len Lr.
// returns false if t is out of range.
__device__ __forceinline__ bool slot_decode(int t, int P, int& r, int& mt, int& Lr)
{
    const int q0 = T_SEQ / P, rem = T_SEQ % P;
    const int nt_hi = (q0 + 64) >> 6;
    const int nt_lo = (q0 + 63) >> 6;
    const int hi_total = rem * nt_hi;
    if (t < hi_total) {
        r = t / nt_hi; mt = t - r * nt_hi; Lr = q0 + 1;
    } else {
        t -= hi_total;
        if (t >= (P - rem) * nt_lo) return false;
        const int rr = t / nt_lo;
        r = rem + rr; mt = t - rr * nt_lo; Lr = q0;
    }
    return true;
}

// ---------------------------------------------------------------------------
// Kernel 0: one-pass fp32 -> bf16 conversion of x, in_proj_w, out_w.
// FUSED item-list build: blocks 0..31 (one per head) also compact the valid
// (bh, slot, chunk) items into a per-head PRIVATE 80-entry region (no atomic),
// rank-interleaved (items[rank*32+bh]) so each head's heaviest item dispatches
// first in the attention grid. Invalid entries = -1.
// ---------------------------------------------------------------------------
#define XGROUPS  (M_ROWS * D_MODEL / 8)        // 524288
#define W1GROUPS (3 * D_MODEL * D_MODEL / 8)   // 98304
#define W2GROUPS (D_MODEL * D_MODEL / 8)       // 32768
#define CVT_GROUPS (XGROUPS + W1GROUPS + W2GROUPS)   // 655360 = 2560*256
#define MAX_ITEMS 2560                         // 32 heads x 80 (P=1 worst case)

__global__ __launch_bounds__(256) void cvt_inputs(
    const float* __restrict__ x, const float* __restrict__ w1,
    const float* __restrict__ w2, unsigned short* __restrict__ xo,
    unsigned short* __restrict__ w1o, unsigned short* __restrict__ w2o,
    const int* __restrict__ periods, int* __restrict__ items)
{
    {
        int i = blockIdx.x * 256 + threadIdx.x;
        const float* src; unsigned short* dst;
        if (i < XGROUPS)                  { src = x;  dst = xo;  }
        else if (i < XGROUPS + W1GROUPS)  { src = w1; dst = w1o; i -= XGROUPS; }
        else                              { src = w2; dst = w2o; i -= XGROUPS + W1GROUPS; }
        const float4* p = (const float4*)(src + (size_t)i * 8);
        float4 a = p[0], b = p[1];
        *(int4*)(dst + (size_t)i * 8) = cvt8(a, b);
    }
    if (blockIdx.x < 32) {
        const int bh = blockIdx.x;
        int P = periods[bh]; if (P < 1) P = 1;
        const int tid  = threadIdx.x;
        const int wave = tid >> 6, lane = tid & 63;
        const int t = 63 - (tid >> 2);           // heavy slots first
        const int c = 3 - (tid & 3);
        int r, mt, Lr;
        const bool valid = slot_decode(t, P, r, mt, Lr) && ((c << 3) <= mt);
        const unsigned long long mask = __ballot(valid);
        const int prefix = __popcll(mask & ((1ull << lane) - 1ull));
        __shared__ int wb[4];
        if (lane == 0) wb[wave] = __popcll(mask);
        if (tid < 80) items[tid * 32 + bh] = -1;
        __syncthreads();
        int base = 0;
        if (wave > 0) base += wb[0];
        if (wave > 1) base += wb[1];
        if (wave > 2) base += wb[2];
        if (valid) items[(base + prefix) * 32 + bh] = (bh << 8) | (t << 2) | c;
    }
}

// ---------------------------------------------------------------------------
// Kernel 1: QKV projection, bf16 MFMA, global_load_lds width-16 staging.
// ---------------------------------------------------------------------------
__global__ __launch_bounds__(256) void qkv_gemm_mfma(
    const unsigned short* __restrict__ X,    // 8192 x 512 bf16
    const unsigned short* __restrict__ W,    // 1536 x 512 bf16
    const float* __restrict__ bias,
    unsigned short* __restrict__ qo, unsigned short* __restrict__ ko,
    unsigned short* __restrict__ vo)
{
    __shared__ unsigned short smem[128 * 128];    // 32 KB: As|Bs, then C-tile
    unsigned short* const As = smem;              // 128 x 64
    unsigned short* const Bs = smem + 128 * 64;   // 128 x 64

    const int bid  = blockIdx.x;
    const int xcd  = bid & 7;
    const int chk_ = bid >> 3;                            // 0..95
    const int row0 = (((chk_ / 12) << 3) + xcd) << 7;
    const int col0 = (chk_ % 12) << 7;

    const int tid  = threadIdx.x;
    const int wave = tid >> 6, lane = tid & 63;
    const int quad = lane >> 4, l15 = lane & 15;
    const int wm   = wave >> 1, wn = wave & 1;
    const int lr8  = lane >> 3;     // row within 8-row staging group
    const int sc   = lane & 7;      // 16B chunk within row

    floatx4 acc[4][4] = {};

    for (int k0 = 0; k0 < D_MODEL; k0 += 64) {
#pragma unroll
        for (int i = 0; i < 4; ++i) {
            const int rb  = (wave << 5) + (i << 3);       // uniform row base
            const int r   = rb + lr8;
            const int csw = sc ^ (r & 7);                 // pre-swizzled source chunk
            gload16(X + (size_t)(row0 + r) * D_MODEL + k0 + (csw << 3),
                    As + (rb << 6));
            gload16(W + (size_t)(col0 + r) * D_MODEL + k0 + (csw << 3),
                    Bs + (rb << 6));
        }
        __syncthreads();

#pragma unroll
        for (int ks = 0; ks < 2; ++ks) {
            short8 af[4], bfr[4];
            const int ch = (ks << 2) + quad;
#pragma unroll
            for (int mt = 0; mt < 4; ++mt) {
                const int row = (wm << 6) + (mt << 4) + l15;
                af[mt] = *(const short8*)(As + (row << 6) + ((ch ^ (row & 7)) << 3));
            }
#pragma unroll
            for (int nt = 0; nt < 4; ++nt) {
                const int col = (wn << 6) + (nt << 4) + l15;
                bfr[nt] = *(const short8*)(Bs + (col << 6) + ((ch ^ (col & 7)) << 3));
            }
#pragma unroll
            for (int mt = 0; mt < 4; ++mt)
#pragma unroll
                for (int nt = 0; nt < 4; ++nt)
                    acc[mt][nt] = __builtin_amdgcn_mfma_f32_16x16x32_bf16(
                        af[mt], bfr[nt], acc[mt][nt], 0, 0, 0);
        }
        __syncthreads();
    }

#pragma unroll
    for (int nt = 0; nt < 4; ++nt) {
        const int ncol = (wn << 6) + (nt << 4) + l15;
        const float bn = bias[col0 + ncol];
#pragma unroll
        for (int mt = 0; mt < 4; ++mt)
#pragma unroll
            for (int reg = 0; reg < 4; ++reg) {
                const int mrow = (wm << 6) + (mt << 4) + (quad << 2) + reg;
                smem[(mrow << 7) + ncol] = f2bf(acc[mt][nt][reg] + bn);
            }
    }
    __syncthreads();
    {
        const int c16  = lane & 15;
        const int rsub = lane >> 4;
        const int n0   = col0 + (c16 << 3);
        const int part = n0 >> 9;
        unsigned short* dst = (part == 0) ? qo : ((part == 1) ? ko : vo);
        const int head = (n0 & 511) >> 6, d0 = n0 & 63;
#pragma unroll
        for (int p = 0; p < 8; ++p) {
            const int ml = (wave << 5) + (p << 2) + rsub;
            const int m  = row0 + ml;
            const int b = m >> 11, t = m & 2047;
            int4 val = *(const int4*)(smem + (ml << 7) + (c16 << 3));
            *(int4*)(dst + ((((size_t)b << 3) + head) * T_SEQ + t) * HD + d0) = val;
        }
    }
}

// ---------------------------------------------------------------------------
// Kernel 2: residue-class flash attention, SWAPPED-QK in-register softmax.
//  * S^T = mfma(K-frag, Q-frag): lane (quad,l15) holds
//      S[k = 16nt+4quad+reg][q = 16wave+l15]
//  * fixed-max base-2 softmax (p = 2^(s*SCALE2-8), exact by shift-invariance)
//    computed entirely in registers: NO P-tilde LDS round trip.
//  * PV contraction k-order is PERMUTED, pi(32ks+8quad+i) =
//      16(2ks+(i>>2)) + 4quad + (i&3),
//    so each lane's packed P-tilde words ARE its PV A-fragments verbatim;
//    the matching permutation is applied to the V^T staging (u32-col cpos).
//  * row-sums: 16 adds/tile into one scalar; reduced once at epilogue
//    (2 shfl_xor across quads + 4 shfl gathers). No MFMA(ones), no Ps reads.
//  * K tiles staged via async global_load_lds (pre-swizzled per-lane source).
// Dense item list (rank-interleaved, heavy-first); blocks with items[bid]<0
// exit immediately. 40 KB LDS -> 4 blocks/CU.
// ---------------------------------------------------------------------------
#define SCALE2 0.18033688011112042f   // 0.125 * log2(e)

__global__ __launch_bounds__(256) void attn_rc_mfma(
    const unsigned short* __restrict__ q, const unsigned short* __restrict__ k,
    const unsigned short* __restrict__ v, const int* __restrict__ periods,
    unsigned short* __restrict__ o,
    unsigned short* __restrict__ Opart, float* __restrict__ Lpart,
    const int* __restrict__ items)
{
    const int idx = items[blockIdx.x];
    if (idx < 0) return;

    __shared__ unsigned short Ks[2][64 * 64];   // [key][hd]; [0] = epilogue scratch
    __shared__ unsigned short Vt[2][64 * 64];   // [hd][kperm]
    __shared__ unsigned short Ps[64 * 64];      // Q tile

    const int bh     = idx >> 8;
    const int t_orig = (idx >> 2) & 63;
    const int c      = idx & 3;
    int P = periods[bh]; if (P < 1) P = 1;
    int r, mt, Lr;
    if (!slot_decode(t_orig, P, r, mt, Lr)) return;   // can't happen; safety
    const int nch  = (mt >> 3) + 1;
    const int kt0  = c << 3;
    const int kend = (kt0 + 7 < mt) ? (kt0 + 7) : mt;
    const int m0   = mt << 6;

    const int tid  = threadIdx.x;
    const int wave = tid >> 6, lane = tid & 63;
    const int quad = lane >> 4, l15 = lane & 15;
    const int vkp  = tid & 31, vhg = tid >> 5;   // V staging: key-pair, hd-group
    // permuted u32-column for V-pair (2vkp, 2vkp+1):
    //   cpos = 16*(vkp>>4) + 4*((vkp&7)>>1) + 2*((vkp>>3)&1) + (vkp&1)
    const int cpos = ((vkp >> 4) << 4) + (((vkp & 7) >> 1) << 2)
                   + (((vkp >> 3) & 1) << 1) + (vkp & 1);
    const int cgrp = cpos >> 2, clo = (cpos & 3) << 2;

    const unsigned short* hq = q + (size_t)bh * T_SEQ * HD;
    const unsigned short* hk = k + (size_t)bh * T_SEQ * HD;
    const unsigned short* hv = v + (size_t)bh * T_SEQ * HD;

    // ---- async-stage Q -> Ps, K(kt0) -> Ks[0]; V(kt0) -> regs -> Vt[0] ----
    {
        const int km0 = kt0 << 6;
#pragma unroll
        for (int i = 0; i < 2; ++i) {
            const int rb  = (wave << 4) + (i << 3);
            const int rr  = rb + (lane >> 3);
            const int csw = ((lane & 7) ^ (rr & 7)) << 3;
            int mq = m0 + rr;  if (mq > Lr - 1) mq = Lr - 1;
            int mk = km0 + rr; if (mk > Lr - 1) mk = Lr - 1;
            gload16(hq + (size_t)(r + mq * P) * HD + csw, Ps + (rb << 6));
            gload16(hk + (size_t)(r + mk * P) * HD + csw, Ks[0] + (rb << 6));
        }
        int mv0 = km0 + (vkp << 1);     if (mv0 > Lr - 1) mv0 = Lr - 1;
        int mv1 = km0 + (vkp << 1) + 1; if (mv1 > Lr - 1) mv1 = Lr - 1;
        int4 va = *(const int4*)(hv + (size_t)(r + mv0 * P) * HD + (vhg << 3));
        int4 vb = *(const int4*)(hv + (size_t)(r + mv1 * P) * HD + (vhg << 3));
        const unsigned short* pa = (const unsigned short*)&va;
        const unsigned short* pb = (const unsigned short*)&vb;
#pragma unroll
        for (int j = 0; j < 8; ++j) {
            const int hd_ = (vhg << 3) + j;
            const unsigned int pk =
                (unsigned int)pa[j] | ((unsigned int)pb[j] << 16);
            *(unsigned int*)((char*)Vt[0] + (hd_ << 7) +
                             ((cgrp ^ (hd_ & 7)) << 4) + clo) = pk;
        }
    }
    __syncthreads();
    short8 qf[2];
#pragma unroll
    for (int ks = 0; ks < 2; ++ks) {
        const int row = (wave << 4) + l15;
        qf[ks] = *(const short8*)(Ps + (row << 6) +
                                  ((((ks << 2) + quad) ^ (row & 7)) << 3));
    }

    floatx4 Oa[4] = {};
    float Lacc = 0.f;                      // partial row-sum (q = 16wave+l15)
    const int qrel = (wave << 4) + l15;    // tile-relative query row

    for (int kt = kt0; kt <= kend; ++kt) {
        const int buf = (kt - kt0) & 1;
        const bool havenext = kt < kend;

        int4 va, vb;
        if (havenext) {
            const int km0 = (kt + 1) << 6;
#pragma unroll
            for (int i = 0; i < 2; ++i) {       // K prefetch: async direct-to-LDS
                const int rb  = (wave << 4) + (i << 3);
                const int rr  = rb + (lane >> 3);
                int mk = km0 + rr; if (mk > Lr - 1) mk = Lr - 1;
                gload16(hk + (size_t)(r + mk * P) * HD +
                            (((lane & 7) ^ (rr & 7)) << 3),
                        Ks[buf ^ 1] + (rb << 6));
            }
            int mv0 = km0 + (vkp << 1);     if (mv0 > Lr - 1) mv0 = Lr - 1;
            int mv1 = km0 + (vkp << 1) + 1; if (mv1 > Lr - 1) mv1 = Lr - 1;
            va = *(const int4*)(hv + (size_t)(r + mv0 * P) * HD + (vhg << 3));
            vb = *(const int4*)(hv + (size_t)(r + mv1 * P) * HD + (vhg << 3));
        }

        // ---- swapped QK^T from Ks[buf]: sacc[nt] = S^T fragments ----
        floatx4 sacc[4] = {};
        __builtin_amdgcn_s_setprio(1);
#pragma unroll
        for (int nt = 0; nt < 4; ++nt) {
            const int row = (nt << 4) + l15;
#pragma unroll
            for (int ks = 0; ks < 2; ++ks) {
                short8 kf = *(const short8*)(Ks[buf] + (row << 6) +
                                             ((((ks << 2) + quad) ^ (row & 7)) << 3));
                sacc[nt] = __builtin_amdgcn_mfma_f32_16x16x32_bf16(
                    kf, qf[ks], sacc[nt], 0, 0, 0);
            }
        }
        __builtin_amdgcn_s_setprio(0);

        // ---- in-register fixed-max softmax + pack into PV A-frags ----
        const bool diag = (kt == mt);
        unsigned int wv[8];    // wv[2nt+h] = bf16 pair, k = 16nt+4quad+2h+{0,1}
        float rs = 0.f;
#pragma unroll
        for (int nt = 0; nt < 4; ++nt) {
            unsigned short bq[4];
#pragma unroll
            for (int reg = 0; reg < 4; ++reg) {
                const int krel = (nt << 4) + (quad << 2) + reg;
                float sv = fmaf(sacc[nt][reg], SCALE2, -8.f);
                if (diag && krel > qrel) sv = -1e30f;   // causal: key > query
                bq[reg] = f2bf(exp2_raw(sv));
                rs += bf2f(bq[reg]);    // sum the ROUNDED value (parity w/ MFMA path)
            }
            wv[(nt << 1)]     = (unsigned int)bq[0] | ((unsigned int)bq[1] << 16);
            wv[(nt << 1) | 1] = (unsigned int)bq[2] | ((unsigned int)bq[3] << 16);
        }
        Lacc += rs;
        uintx4 wA = {wv[0], wv[1], wv[2], wv[3]};
        uintx4 wB = {wv[4], wv[5], wv[6], wv[7]};
        const short8 pa0 = __builtin_bit_cast(short8, wA);  // A-frag ks=0
        const short8 pa1 = __builtin_bit_cast(short8, wB);  // A-frag ks=1

        // ---- PV from permuted Vt[buf] ----
        __builtin_amdgcn_s_setprio(1);
#pragma unroll
        for (int nt = 0; nt < 4; ++nt) {
            const int row = (nt << 4) + l15;
#pragma unroll
            for (int ks = 0; ks < 2; ++ks) {
                short8 vf = *(const short8*)(Vt[buf] + (row << 6) +
                                             ((((ks << 2) + quad) ^ (row & 7)) << 3));
                Oa[nt] = __builtin_amdgcn_mfma_f32_16x16x32_bf16(
                    ks ? pa1 : pa0, vf, Oa[nt], 0, 0, 0);
            }
        }
        __builtin_amdgcn_s_setprio(0);

        // ---- write next V tile (permuted) into the other buffer ----
        if (havenext) {
            const unsigned short* pa = (const unsigned short*)&va;
            const unsigned short* pb = (const unsigned short*)&vb;
#pragma unroll
            for (int j = 0; j < 8; ++j) {
                const int hd_ = (vhg << 3) + j;
                const unsigned int pk =
                    (unsigned int)pa[j] | ((unsigned int)pb[j] << 16);
                *(unsigned int*)((char*)Vt[buf ^ 1] + (hd_ << 7) +
                                 ((cgrp ^ (hd_ & 7)) << 4) + clo) = pk;
            }
        }
        __syncthreads();
    }

    // ---- finalize row sums: reduce across quads, gather per accumulator q ----
    Lacc += __shfl_xor(Lacc, 16);
    Lacc += __shfl_xor(Lacc, 32);
    float l_i[4];
#pragma unroll
    for (int reg = 0; reg < 4; ++reg)
        l_i[reg] = __shfl(Lacc, (lane & 48) | (quad << 2) | reg);

    if (nch == 1) {
        // ---- direct epilogue: normalize + scatter via LDS scratch ----
        // (write/read rows are wave-private; no barrier needed)
#pragma unroll
        for (int reg = 0; reg < 4; ++reg) {
            const float invl = 1.f / l_i[reg];
            const int row = (wave << 4) + (quad << 2) + reg;
#pragma unroll
            for (int nt = 0; nt < 4; ++nt)
                Ks[0][(row << 6) + (nt << 4) + l15] = f2bf(Oa[nt][reg] * invl);
        }
        const int lrow = lane >> 2;
        const int chk  = (lane & 3) << 1;
        const int ml   = (wave << 4) + lrow;
        const int m    = m0 + ml;
        if (m < Lr) {
            const size_t base = ((size_t)bh * T_SEQ + (r + m * P)) * HD;
            int4 w0 = *(const int4*)(Ks[0] + (ml << 6) + (chk << 3));
            int4 w1 = *(const int4*)(Ks[0] + (ml << 6) + ((chk + 1) << 3));
            *(int4*)(o + base + (chk << 3))       = w0;
            *(int4*)(o + base + ((chk + 1) << 3)) = w1;
        }
    } else {
        // ---- partial epilogue: unnormalized O + l, slot=(bh,t,chunk) ----
        const size_t slot = ((size_t)((bh << 6) + t_orig) << 2) + c;
#pragma unroll
        for (int reg = 0; reg < 4; ++reg) {
            const int row = (wave << 4) + (quad << 2) + reg;
#pragma unroll
            for (int nt = 0; nt < 4; ++nt)
                Ks[0][(row << 6) + (nt << 4) + l15] = f2bf(Oa[nt][reg]);
            if (l15 == 0)
                Lpart[slot * 64 + row] = l_i[reg];
        }
        const int lrow = lane >> 2;
        const int chk  = (lane & 3) << 1;
        const int ml   = (wave << 4) + lrow;
        unsigned short* dst = Opart + slot * 4096 + (ml << 6);
        *(int4*)(dst + (chk << 3))       = *(const int4*)(Ks[0] + (ml << 6) + (chk << 3));
        *(int4*)(dst + ((chk + 1) << 3)) = *(const int4*)(Ks[0] + (ml << 6) + ((chk + 1) << 3));
    }
}

// ---------------------------------------------------------------------------
// Kernel 2b: merge 2..4 chunks of multi-chunk slots (mt >= 8).
// Fixed-max softmax -> all chunks share the same max: merge is a plain sum.
// ---------------------------------------------------------------------------
__global__ __launch_bounds__(256) void reduce_rc(
    const int* __restrict__ periods,
    const unsigned short* __restrict__ Opart, const float* __restrict__ Lpart,
    unsigned short* __restrict__ o)
{
    const int bh = blockIdx.y;
    int P = periods[bh]; if (P < 1) P = 1;
    const int t = blockIdx.x;
    int r, mt, Lr;
    if (!slot_decode(t, P, r, mt, Lr)) return;
    const int nch = (mt >> 3) + 1;
    if (nch < 2) return;

    const int tid = threadIdx.x;
    const int row = tid >> 2;
    const int cg  = (tid & 3) << 4;             // 16 cols per thread
    const int m   = (mt << 6) + row;
    if (m >= Lr) return;

    const size_t slot0 = (size_t)((bh << 6) + t) << 2;

    float lsum = 0.f;
    for (int cc = 0; cc < nch; ++cc)
        lsum += Lpart[(slot0 + cc) * 64 + row];
    const float inv = 1.f / lsum;

    float ov[16] = {};
    for (int cc = 0; cc < nch; ++cc) {
        const unsigned short* p = Opart + (slot0 + cc) * 4096 + (row << 6) + cg;
#pragma unroll
        for (int j = 0; j < 16; ++j) ov[j] += bf2f(p[j]);
    }
    unsigned short outv[16];
#pragma unroll
    for (int j = 0; j < 16; ++j) outv[j] = f2bf(ov[j] * inv);

    unsigned short* dst = o + ((size_t)bh * T_SEQ + (r + m * P)) * HD + cg;
    *(int4*)dst       = *(const int4*)&outv[0];
    *(int4*)(dst + 8) = *(const int4*)&outv[8];
}

// ---------------------------------------------------------------------------
// Kernel 3: out projection, bf16 MFMA, global_load_lds staging.
// Tile 64x128, grid (128,4) = 512 blocks -> 2 blocks/CU.
// ---------------------------------------------------------------------------
__global__ __launch_bounds__(256) void out_gemm_mfma(
    const unsigned short* __restrict__ A,
    const unsigned short* __restrict__ W,   // 512 x 512 bf16
    const float* __restrict__ bias,
    float* __restrict__ out)
{
    __shared__ unsigned short As[64 * 64];    // 8 KB
    __shared__ unsigned short Bs[128 * 64];   // 16 KB

    const int tid  = threadIdx.x;
    const int wave = tid >> 6, lane = tid & 63;
    const int quad = lane >> 4, l15 = lane & 15;
    const int wm   = wave >> 1, wn = wave & 1;   // 2x2 wave grid: 32-row x 64-col
    const int row0 = blockIdx.x * 64;
    const int col0 = blockIdx.y * 128;
    const int lr8  = lane >> 3;
    const int sc   = lane & 7;

    floatx4 acc[2][4] = {};

    for (int k0 = 0; k0 < D_MODEL; k0 += 64) {
        const int h = k0 >> 6;
#pragma unroll
        for (int i = 0; i < 4; ++i) {          // B: 128 rows of W
            const int rb  = (wave << 5) + (i << 3);
            const int r   = rb + lr8;
            const int csw = sc ^ (r & 7);
            gload16(W + (size_t)(col0 + r) * D_MODEL + k0 + (csw << 3),
                    Bs + (rb << 6));
        }
#pragma unroll
        for (int i = 0; i < 2; ++i) {          // A: 64 rows, head-major gather
            const int rb  = (wave << 4) + (i << 3);
            const int r   = rb + lr8;
            const int csw = sc ^ (r & 7);
            const int rg = row0 + r;
            const int b = rg >> 11, t = rg & 2047;
            gload16(A + ((((size_t)b << 3) + h) * T_SEQ + t) * HD + (csw << 3),
                    As + (rb << 6));
        }
        __syncthreads();

#pragma unroll
        for (int ks = 0; ks < 2; ++ks) {
            short8 af[2], bfr[4];
            const int ch = (ks << 2) + quad;
#pragma unroll
            for (int mt = 0; mt < 2; ++mt) {
                const int row = (wm << 5) + (mt << 4) + l15;
                af[mt] = *(const short8*)(As + (row << 6) + ((ch ^ (row & 7)) << 3));
            }
#pragma unroll
            for (int nt = 0; nt < 4; ++nt) {
                const int col = (wn << 6) + (nt << 4) + l15;
                bfr[nt] = *(const short8*)(Bs + (col << 6) + ((ch ^ (col & 7)) << 3));
            }
#pragma unroll
            for (int mt = 0; mt < 2; ++mt)
#pragma unroll
                for (int nt = 0; nt < 4; ++nt)
                    acc[mt][nt] = __builtin_amdgcn_mfma_f32_16x16x32_bf16(
                        af[mt], bfr[nt], acc[mt][nt], 0, 0, 0);
        }
        __syncthreads();
    }

#pragma unroll
    for (int nt = 0; nt < 4; ++nt) {
        const int n = col0 + (wn << 6) + (nt << 4) + l15;
        const float bn = bias[n];
#pragma unroll
        for (int mt = 0; mt < 2; ++mt) {
#pragma unroll
            for (int reg = 0; reg < 4; ++reg) {
                const int m = row0 + (wm << 5) + (mt << 4) + (quad << 2) + reg;
                out[(size_t)m * D_MODEL + n] = acc[mt][nt][reg] + bn;
            }
        }
    }
}

// ---------------------------------------------------------------------------
extern "C" void kernel_launch(void* const* d_in, const int* in_sizes, int n_in,
                              void* d_out, int out_size, void* d_ws, size_t ws_size,
                              hipStream_t stream)
{
    const float* x        = (const float*)d_in[0];
    const int*   periods  = (const int*)  d_in[1];
    const float* in_w     = (const float*)d_in[2];
    const float* in_b     = (const float*)d_in[3];
    const float* out_w    = (const float*)d_in[4];
    const float* out_b    = (const float*)d_in[5];
    float*       out      = (float*)d_out;

    const size_t TENS = (size_t)BATCH * NHEAD * T_SEQ * HD;   // 4,194,304
    unsigned short* qb    = (unsigned short*)d_ws;
    unsigned short* kb    = qb + TENS;
    unsigned short* vb    = kb + TENS;
    unsigned short* aob   = vb + TENS;
    unsigned short* Opart = aob + TENS;                // 8192 slots x 4096 bf16
    float*          Lpart = (float*)(Opart + (size_t)8192 * 4096);
    unsigned short* Xb    = (unsigned short*)(Lpart + (size_t)8192 * 64);
    unsigned short* W1b   = Xb + (size_t)M_ROWS * D_MODEL;          // 1536x512
    unsigned short* W2b   = W1b + (size_t)3 * D_MODEL * D_MODEL;    // 512x512
    int*            items = (int*)(W2b + (size_t)D_MODEL * D_MODEL); // 2560 ints
    // ws usage: 4*8MB + 64MB + 2MB + 8+1.5+0.5MB + 10KB ~= 108 MiB

    // 0) fp32 -> bf16 conversion of X, in_proj_w, out_w + fused item build
    cvt_inputs<<<CVT_GROUPS / 256, 256, 0, stream>>>(x, in_w, out_w,
                                                     Xb, W1b, W2b,
                                                     periods, items);

    // 1) QKV projection (bf16 MFMA, async-staged), XCD-swizzled flat grid
    qkv_gemm_mfma<<<(M_ROWS / 128) * ((3 * D_MODEL) / 128), 256, 0, stream>>>(
        Xb, W1b, in_b, qb, kb, vb);

    // 2) flash attention over the dense item list (swapped-QK in-reg softmax)
    attn_rc_mfma<<<MAX_ITEMS, 256, 0, stream>>>(qb, kb, vb, periods, aob,
                                                Opart, Lpart, items);
    // 2b) merge chunks (slots with mt >= 8)
    reduce_rc<<<dim3(64, BATCH * NHEAD), 256, 0, stream>>>(
        periods, Opart, Lpart, aob);

    // 3) out projection (bf16 MFMA, bf16 weights), 64x128 tiles, 2 blocks/CU
    dim3 g3(M_ROWS / 64, D_MODEL / 128);          // 128 x 4
    out_gemm_mfma<<<g3, 256, 0, stream>>>(aob, W2b, out_b, out);
}

// Round 7
// 134.771 us; speedup vs baseline: 1.1651x; 1.1651x over previous
//
#include <hip/hip_runtime.h>
#include <math.h>

#define D_MODEL 512
#define NHEAD   8
#define HD      64
#define T_SEQ   2048
#define BATCH   4
#define M_ROWS  (BATCH * T_SEQ)   // 8192

typedef __attribute__((ext_vector_type(8))) short        short8;   // 8 bf16
typedef __attribute__((ext_vector_type(4))) float        floatx4;
typedef __attribute__((ext_vector_type(4))) unsigned int uintx4;

// round-to-nearest-even fp32 -> bf16 (bit math; inputs finite)
__device__ __forceinline__ unsigned short f2bf(float f) {
    unsigned int u = __float_as_uint(f);
    unsigned int r = u + 0x7FFFu + ((u >> 16) & 1u);
    return (unsigned short)(r >> 16);
}

__device__ __forceinline__ float bf2f(unsigned short u) {
    return __uint_as_float((unsigned int)u << 16);
}

// raw v_exp_f32: D = 2^S0 (base-2 exponential, no hidden *log2e multiply)
__device__ __forceinline__ float exp2_raw(float x) {
    float r;
    asm("v_exp_f32 %0, %1" : "=v"(r) : "v"(x));
    return r;
}

// pack 8 fp32 -> 8 bf16 in an int4
__device__ __forceinline__ int4 cvt8(float4 a, float4 b) {
    union { unsigned short u[8]; int4 v; } r;
    r.u[0] = f2bf(a.x); r.u[1] = f2bf(a.y); r.u[2] = f2bf(a.z); r.u[3] = f2bf(a.w);
    r.u[4] = f2bf(b.x); r.u[5] = f2bf(b.y); r.u[6] = f2bf(b.z); r.u[7] = f2bf(b.w);
    return r.v;
}

// async global->LDS, 16 B per lane; LDS dest = base + lane*16 (wave-uniform base)
__device__ __forceinline__ void gload16(const void* g, void* l) {
    __builtin_amdgcn_global_load_lds(
        (const __attribute__((address_space(1))) void*)g,
        (__attribute__((address_space(3))) void*)l, 16, 0, 0);
}

// decompose tile-slot t for head period P: residue r, q-tile mt, subseq len Lr.
// returns false if t is out of range.
__device__ __forceinline__ bool slot_decode(int t, int P, int& r, int& mt, int& Lr)
{
    const int q0 = T_SEQ / P, rem = T_SEQ % P;
    const int nt_hi = (q0 + 64) >> 6;
    const int nt_lo = (q0 + 63) >> 6;
    const int hi_total = rem * nt_hi;
    if (t < hi_total) {
        r = t / nt_hi; mt = t - r * nt_hi; Lr = q0 + 1;
    } else {
        t -= hi_total;
        if (t >= (P - rem) * nt_lo) return false;
        const int rr = t / nt_lo;
        r = rem + rr; mt = t - rr * nt_lo; Lr = q0;
    }
    return true;
}

// ---------------------------------------------------------------------------
// Kernel 0: one-pass fp32 -> bf16 conversion of x, in_proj_w, out_w.
// FUSED item-list build: blocks 0..31 (one per head) compact the valid
// (bh, slot, chunk) items into a per-head PRIVATE 80-entry region.
// PLACEMENT (the R6 lesson): per-head CONTIGUOUS blocks spread across XCDs
// (blockIdx%8 is the XCD), so each head's work uses the whole chip. The
// rank*32+bh interleave pinned every head to ONE XCD (32 == 0 mod 8) and the
// heavy P=1 head serialized on 1/8 of the machine. Layout here:
//   items[bh*80 + (rank + bh) % 80]   (rotation de-correlates rank<->XCD,
//                                      since 80 == 0 mod 8 too)
// Invalid entries = -1; heavy ranks first within each head.
// ---------------------------------------------------------------------------
#define XGROUPS  (M_ROWS * D_MODEL / 8)        // 524288
#define W1GROUPS (3 * D_MODEL * D_MODEL / 8)   // 98304
#define W2GROUPS (D_MODEL * D_MODEL / 8)       // 32768
#define CVT_GROUPS (XGROUPS + W1GROUPS + W2GROUPS)   // 655360 = 2560*256
#define MAX_ITEMS 2560                         // 32 heads x 80 (P=1 worst case)

__global__ __launch_bounds__(256) void cvt_inputs(
    const float* __restrict__ x, const float* __restrict__ w1,
    const float* __restrict__ w2, unsigned short* __restrict__ xo,
    unsigned short* __restrict__ w1o, unsigned short* __restrict__ w2o,
    const int* __restrict__ periods, int* __restrict__ items)
{
    {
        int i = blockIdx.x * 256 + threadIdx.x;
        const float* src; unsigned short* dst;
        if (i < XGROUPS)                  { src = x;  dst = xo;  }
        else if (i < XGROUPS + W1GROUPS)  { src = w1; dst = w1o; i -= XGROUPS; }
        else                              { src = w2; dst = w2o; i -= XGROUPS + W1GROUPS; }
        const float4* p = (const float4*)(src + (size_t)i * 8);
        float4 a = p[0], b = p[1];
        *(int4*)(dst + (size_t)i * 8) = cvt8(a, b);
    }
    if (blockIdx.x < 32) {
        const int bh = blockIdx.x;
        int P = periods[bh]; if (P < 1) P = 1;
        const int tid  = threadIdx.x;
        const int wave = tid >> 6, lane = tid & 63;
        const int t = 63 - (tid >> 2);           // heavy slots first
        const int c = 3 - (tid & 3);
        int r, mt, Lr;
        const bool valid = slot_decode(t, P, r, mt, Lr) && ((c << 3) <= mt);
        const unsigned long long mask = __ballot(valid);
        const int prefix = __popcll(mask & ((1ull << lane) - 1ull));
        __shared__ int wb[4];
        if (lane == 0) wb[wave] = __popcll(mask);
        if (tid < 80) items[bh * 80 + tid] = -1;
        __syncthreads();
        int base = 0;
        if (wave > 0) base += wb[0];
        if (wave > 1) base += wb[1];
        if (wave > 2) base += wb[2];
        if (valid) {
            const int rank = base + prefix;
            items[bh * 80 + ((rank + bh) % 80)] = (bh << 8) | (t << 2) | c;
        }
    }
}

// ---------------------------------------------------------------------------
// Kernel 1: QKV projection, bf16 MFMA, global_load_lds width-16 staging.
// ---------------------------------------------------------------------------
__global__ __launch_bounds__(256) void qkv_gemm_mfma(
    const unsigned short* __restrict__ X,    // 8192 x 512 bf16
    const unsigned short* __restrict__ W,    // 1536 x 512 bf16
    const float* __restrict__ bias,
    unsigned short* __restrict__ qo, unsigned short* __restrict__ ko,
    unsigned short* __restrict__ vo)
{
    __shared__ unsigned short smem[128 * 128];    // 32 KB: As|Bs, then C-tile
    unsigned short* const As = smem;              // 128 x 64
    unsigned short* const Bs = smem + 128 * 64;   // 128 x 64

    const int bid  = blockIdx.x;
    const int xcd  = bid & 7;
    const int chk_ = bid >> 3;                            // 0..95
    const int row0 = (((chk_ / 12) << 3) + xcd) << 7;
    const int col0 = (chk_ % 12) << 7;

    const int tid  = threadIdx.x;
    const int wave = tid >> 6, lane = tid & 63;
    const int quad = lane >> 4, l15 = lane & 15;
    const int wm   = wave >> 1, wn = wave & 1;
    const int lr8  = lane >> 3;     // row within 8-row staging group
    const int sc   = lane & 7;      // 16B chunk within row

    floatx4 acc[4][4] = {};

    for (int k0 = 0; k0 < D_MODEL; k0 += 64) {
#pragma unroll
        for (int i = 0; i < 4; ++i) {
            const int rb  = (wave << 5) + (i << 3);       // uniform row base
            const int r   = rb + lr8;
            const int csw = sc ^ (r & 7);                 // pre-swizzled source chunk
            gload16(X + (size_t)(row0 + r) * D_MODEL + k0 + (csw << 3),
                    As + (rb << 6));
            gload16(W + (size_t)(col0 + r) * D_MODEL + k0 + (csw << 3),
                    Bs + (rb << 6));
        }
        __syncthreads();

#pragma unroll
        for (int ks = 0; ks < 2; ++ks) {
            short8 af[4], bfr[4];
            const int ch = (ks << 2) + quad;
#pragma unroll
            for (int mt = 0; mt < 4; ++mt) {
                const int row = (wm << 6) + (mt << 4) + l15;
                af[mt] = *(const short8*)(As + (row << 6) + ((ch ^ (row & 7)) << 3));
            }
#pragma unroll
            for (int nt = 0; nt < 4; ++nt) {
                const int col = (wn << 6) + (nt << 4) + l15;
                bfr[nt] = *(const short8*)(Bs + (col << 6) + ((ch ^ (col & 7)) << 3));
            }
#pragma unroll
            for (int mt = 0; mt < 4; ++mt)
#pragma unroll
                for (int nt = 0; nt < 4; ++nt)
                    acc[mt][nt] = __builtin_amdgcn_mfma_f32_16x16x32_bf16(
                        af[mt], bfr[nt], acc[mt][nt], 0, 0, 0);
        }
        __syncthreads();
    }

#pragma unroll
    for (int nt = 0; nt < 4; ++nt) {
        const int ncol = (wn << 6) + (nt << 4) + l15;
        const float bn = bias[col0 + ncol];
#pragma unroll
        for (int mt = 0; mt < 4; ++mt)
#pragma unroll
            for (int reg = 0; reg < 4; ++reg) {
                const int mrow = (wm << 6) + (mt << 4) + (quad << 2) + reg;
                smem[(mrow << 7) + ncol] = f2bf(acc[mt][nt][reg] + bn);
            }
    }
    __syncthreads();
    {
        const int c16  = lane & 15;
        const int rsub = lane >> 4;
        const int n0   = col0 + (c16 << 3);
        const int part = n0 >> 9;
        unsigned short* dst = (part == 0) ? qo : ((part == 1) ? ko : vo);
        const int head = (n0 & 511) >> 6, d0 = n0 & 63;
#pragma unroll
        for (int p = 0; p < 8; ++p) {
            const int ml = (wave << 5) + (p << 2) + rsub;
            const int m  = row0 + ml;
            const int b = m >> 11, t = m & 2047;
            int4 val = *(const int4*)(smem + (ml << 7) + (c16 << 3));
            *(int4*)(dst + ((((size_t)b << 3) + head) * T_SEQ + t) * HD + d0) = val;
        }
    }
}

// ---------------------------------------------------------------------------
// Kernel 2: residue-class flash attention, SWAPPED-QK in-register softmax.
//  * S^T = mfma(K-frag, Q-frag): lane (quad,l15) holds
//      S[k = 16nt+4quad+reg][q = 16wave+l15]
//  * fixed-max base-2 softmax (p = 2^(s*SCALE2-8), exact by shift-invariance)
//    computed entirely in registers: NO P-tilde LDS round trip.
//  * PV contraction k-order is PERMUTED, pi(32ks+8quad+i) =
//      16(2ks+(i>>2)) + 4quad + (i&3),
//    so each lane's packed P-tilde words ARE its PV A-fragments verbatim;
//    the matching permutation is applied to the V^T staging (u32-col cpos).
//  * row-sums: 16 adds/tile into one scalar; reduced once at epilogue.
//  * K tiles staged via async global_load_lds (pre-swizzled per-lane source).
// Dense item list, per-head contiguous (XCD-spread); items[bid]<0 -> exit.
// 40 KB LDS -> 4 blocks/CU.
// ---------------------------------------------------------------------------
#define SCALE2 0.18033688011112042f   // 0.125 * log2(e)

__global__ __launch_bounds__(256) void attn_rc_mfma(
    const unsigned short* __restrict__ q, const unsigned short* __restrict__ k,
    const unsigned short* __restrict__ v, const int* __restrict__ periods,
    unsigned short* __restrict__ o,
    unsigned short* __restrict__ Opart, float* __restrict__ Lpart,
    const int* __restrict__ items)
{
    const int idx = items[blockIdx.x];
    if (idx < 0) return;

    __shared__ unsigned short Ks[2][64 * 64];   // [key][hd]; [0] = epilogue scratch
    __shared__ unsigned short Vt[2][64 * 64];   // [hd][kperm]
    __shared__ unsigned short Ps[64 * 64];      // Q tile

    const int bh     = idx >> 8;
    const int t_orig = (idx >> 2) & 63;
    const int c      = idx & 3;
    int P = periods[bh]; if (P < 1) P = 1;
    int r, mt, Lr;
    if (!slot_decode(t_orig, P, r, mt, Lr)) return;   // can't happen; safety
    const int nch  = (mt >> 3) + 1;
    const int kt0  = c << 3;
    const int kend = (kt0 + 7 < mt) ? (kt0 + 7) : mt;
    const int m0   = mt << 6;

    const int tid  = threadIdx.x;
    const int wave = tid >> 6, lane = tid & 63;
    const int quad = lane >> 4, l15 = lane & 15;
    const int vkp  = tid & 31, vhg = tid >> 5;   // V staging: key-pair, hd-group
    // permuted u32-column for V-pair (2vkp, 2vkp+1):
    //   cpos = 16*(vkp>>4) + 4*((vkp&7)>>1) + 2*((vkp>>3)&1) + (vkp&1)
    const int cpos = ((vkp >> 4) << 4) + (((vkp & 7) >> 1) << 2)
                   + (((vkp >> 3) & 1) << 1) + (vkp & 1);
    const int cgrp = cpos >> 2, clo = (cpos & 3) << 2;

    const unsigned short* hq = q + (size_t)bh * T_SEQ * HD;
    const unsigned short* hk = k + (size_t)bh * T_SEQ * HD;
    const unsigned short* hv = v + (size_t)bh * T_SEQ * HD;

    // ---- async-stage Q -> Ps, K(kt0) -> Ks[0]; V(kt0) -> regs -> Vt[0] ----
    {
        const int km0 = kt0 << 6;
#pragma unroll
        for (int i = 0; i < 2; ++i) {
            const int rb  = (wave << 4) + (i << 3);
            const int rr  = rb + (lane >> 3);
            const int csw = ((lane & 7) ^ (rr & 7)) << 3;
            int mq = m0 + rr;  if (mq > Lr - 1) mq = Lr - 1;
            int mk = km0 + rr; if (mk > Lr - 1) mk = Lr - 1;
            gload16(hq + (size_t)(r + mq * P) * HD + csw, Ps + (rb << 6));
            gload16(hk + (size_t)(r + mk * P) * HD + csw, Ks[0] + (rb << 6));
        }
        int mv0 = km0 + (vkp << 1);     if (mv0 > Lr - 1) mv0 = Lr - 1;
        int mv1 = km0 + (vkp << 1) + 1; if (mv1 > Lr - 1) mv1 = Lr - 1;
        int4 va = *(const int4*)(hv + (size_t)(r + mv0 * P) * HD + (vhg << 3));
        int4 vb = *(const int4*)(hv + (size_t)(r + mv1 * P) * HD + (vhg << 3));
        const unsigned short* pa = (const unsigned short*)&va;
        const unsigned short* pb = (const unsigned short*)&vb;
#pragma unroll
        for (int j = 0; j < 8; ++j) {
            const int hd_ = (vhg << 3) + j;
            const unsigned int pk =
                (unsigned int)pa[j] | ((unsigned int)pb[j] << 16);
            *(unsigned int*)((char*)Vt[0] + (hd_ << 7) +
                             ((cgrp ^ (hd_ & 7)) << 4) + clo) = pk;
        }
    }
    __syncthreads();
    short8 qf[2];
#pragma unroll
    for (int ks = 0; ks < 2; ++ks) {
        const int row = (wave << 4) + l15;
        qf[ks] = *(const short8*)(Ps + (row << 6) +
                                  ((((ks << 2) + quad) ^ (row & 7)) << 3));
    }

    floatx4 Oa[4] = {};
    float Lacc = 0.f;                      // partial row-sum (q = 16wave+l15)
    const int qrel = (wave << 4) + l15;    // tile-relative query row

    for (int kt = kt0; kt <= kend; ++kt) {
        const int buf = (kt - kt0) & 1;
        const bool havenext = kt < kend;

        int4 va, vb;
        if (havenext) {
            const int km0 = (kt + 1) << 6;
#pragma unroll
            for (int i = 0; i < 2; ++i) {       // K prefetch: async direct-to-LDS
                const int rb  = (wave << 4) + (i << 3);
                const int rr  = rb + (lane >> 3);
                int mk = km0 + rr; if (mk > Lr - 1) mk = Lr - 1;
                gload16(hk + (size_t)(r + mk * P) * HD +
                            (((lane & 7) ^ (rr & 7)) << 3),
                        Ks[buf ^ 1] + (rb << 6));
            }
            int mv0 = km0 + (vkp << 1);     if (mv0 > Lr - 1) mv0 = Lr - 1;
            int mv1 = km0 + (vkp << 1) + 1; if (mv1 > Lr - 1) mv1 = Lr - 1;
            va = *(const int4*)(hv + (size_t)(r + mv0 * P) * HD + (vhg << 3));
            vb = *(const int4*)(hv + (size_t)(r + mv1 * P) * HD + (vhg << 3));
        }

        // ---- swapped QK^T from Ks[buf]: sacc[nt] = S^T fragments ----
        floatx4 sacc[4] = {};
        __builtin_amdgcn_s_setprio(1);
#pragma unroll
        for (int nt = 0; nt < 4; ++nt) {
            const int row = (nt << 4) + l15;
#pragma unroll
            for (int ks = 0; ks < 2; ++ks) {
                short8 kf = *(const short8*)(Ks[buf] + (row << 6) +
                                             ((((ks << 2) + quad) ^ (row & 7)) << 3));
                sacc[nt] = __builtin_amdgcn_mfma_f32_16x16x32_bf16(
                    kf, qf[ks], sacc[nt], 0, 0, 0);
            }
        }
        __builtin_amdgcn_s_setprio(0);

        // ---- in-register fixed-max softmax + pack into PV A-frags ----
        const bool diag = (kt == mt);
        unsigned int wv[8];    // wv[2nt+h] = bf16 pair, k = 16nt+4quad+2h+{0,1}
        float rs = 0.f;
#pragma unroll
        for (int nt = 0; nt < 4; ++nt) {
            unsigned short bq[4];
#pragma unroll
            for (int reg = 0; reg < 4; ++reg) {
                const int krel = (nt << 4) + (quad << 2) + reg;
                float sv = fmaf(sacc[nt][reg], SCALE2, -8.f);
                if (diag && krel > qrel) sv = -1e30f;   // causal: key > query
                bq[reg] = f2bf(exp2_raw(sv));
                rs += bf2f(bq[reg]);    // sum the ROUNDED value (parity w/ MFMA path)
            }
            wv[(nt << 1)]     = (unsigned int)bq[0] | ((unsigned int)bq[1] << 16);
            wv[(nt << 1) | 1] = (unsigned int)bq[2] | ((unsigned int)bq[3] << 16);
        }
        Lacc += rs;
        uintx4 wA = {wv[0], wv[1], wv[2], wv[3]};
        uintx4 wB = {wv[4], wv[5], wv[6], wv[7]};
        const short8 pa0 = __builtin_bit_cast(short8, wA);  // A-frag ks=0
        const short8 pa1 = __builtin_bit_cast(short8, wB);  // A-frag ks=1

        // ---- PV from permuted Vt[buf] ----
        __builtin_amdgcn_s_setprio(1);
#pragma unroll
        for (int nt = 0; nt < 4; ++nt) {
            const int row = (nt << 4) + l15;
#pragma unroll
            for (int ks = 0; ks < 2; ++ks) {
                short8 vf = *(const short8*)(Vt[buf] + (row << 6) +
                                             ((((ks << 2) + quad) ^ (row & 7)) << 3));
                Oa[nt] = __builtin_amdgcn_mfma_f32_16x16x32_bf16(
                    ks ? pa1 : pa0, vf, Oa[nt], 0, 0, 0);
            }
        }
        __builtin_amdgcn_s_setprio(0);

        // ---- write next V tile (permuted) into the other buffer ----
        if (havenext) {
            const unsigned short* pa = (const unsigned short*)&va;
            const unsigned short* pb = (const unsigned short*)&vb;
#pragma unroll
            for (int j = 0; j < 8; ++j) {
                const int hd_ = (vhg << 3) + j;
                const unsigned int pk =
                    (unsigned int)pa[j] | ((unsigned int)pb[j] << 16);
                *(unsigned int*)((char*)Vt[buf ^ 1] + (hd_ << 7) +
                                 ((cgrp ^ (hd_ & 7)) << 4) + clo) = pk;
            }
        }
        __syncthreads();
    }

    // ---- finalize row sums: reduce across quads, gather per accumulator q ----
    Lacc += __shfl_xor(Lacc, 16);
    Lacc += __shfl_xor(Lacc, 32);
    float l_i[4];
#pragma unroll
    for (int reg = 0; reg < 4; ++reg)
        l_i[reg] = __shfl(Lacc, (lane & 48) | (quad << 2) | reg);

    if (nch == 1) {
        // ---- direct epilogue: normalize + scatter via LDS scratch ----
        // (write/read rows are wave-private; no barrier needed)
#pragma unroll
        for (int reg = 0; reg < 4; ++reg) {
            const float invl = 1.f / l_i[reg];
            const int row = (wave << 4) + (quad << 2) + reg;
#pragma unroll
            for (int nt = 0; nt < 4; ++nt)
                Ks[0][(row << 6) + (nt << 4) + l15] = f2bf(Oa[nt][reg] * invl);
        }
        const int lrow = lane >> 2;
        const int chk  = (lane & 3) << 1;
        const int ml   = (wave << 4) + lrow;
        const int m    = m0 + ml;
        if (m < Lr) {
            const size_t base = ((size_t)bh * T_SEQ + (r + m * P)) * HD;
            int4 w0 = *(const int4*)(Ks[0] + (ml << 6) + (chk << 3));
            int4 w1 = *(const int4*)(Ks[0] + (ml << 6) + ((chk + 1) << 3));
            *(int4*)(o + base + (chk << 3))       = w0;
            *(int4*)(o + base + ((chk + 1) << 3)) = w1;
        }
    } else {
        // ---- partial epilogue: unnormalized O + l, slot=(bh,t,chunk) ----
        const size_t slot = ((size_t)((bh << 6) + t_orig) << 2) + c;
#pragma unroll
        for (int reg = 0; reg < 4; ++reg) {
            const int row = (wave << 4) + (quad << 2) + reg;
#pragma unroll
            for (int nt = 0; nt < 4; ++nt)
                Ks[0][(row << 6) + (nt << 4) + l15] = f2bf(Oa[nt][reg]);
            if (l15 == 0)
                Lpart[slot * 64 + row] = l_i[reg];
        }
        const int lrow = lane >> 2;
        const int chk  = (lane & 3) << 1;
        const int ml   = (wave << 4) + lrow;
        unsigned short* dst = Opart + slot * 4096 + (ml << 6);
        *(int4*)(dst + (chk << 3))       = *(const int4*)(Ks[0] + (ml << 6) + (chk << 3));
        *(int4*)(dst + ((chk + 1) << 3)) = *(const int4*)(Ks[0] + (ml << 6) + ((chk + 1) << 3));
    }
}

// ---------------------------------------------------------------------------
// Kernel 2b: merge 2..4 chunks of multi-chunk slots (mt >= 8).
// Fixed-max softmax -> all chunks share the same max: merge is a plain sum.
// ---------------------------------------------------------------------------
__global__ __launch_bounds__(256) void reduce_rc(
    const int* __restrict__ periods,
    const unsigned short* __restrict__ Opart, const float* __restrict__ Lpart,
    unsigned short* __restrict__ o)
{
    const int bh = blockIdx.y;
    int P = periods[bh]; if (P < 1) P = 1;
    const int t = blockIdx.x;
    int r, mt, Lr;
    if (!slot_decode(t, P, r, mt, Lr)) return;
    const int nch = (mt >> 3) + 1;
    if (nch < 2) return;

    const int tid = threadIdx.x;
    const int row = tid >> 2;
    const int cg  = (tid & 3) << 4;             // 16 cols per thread
    const int m   = (mt << 6) + row;
    if (m >= Lr) return;

    const size_t slot0 = (size_t)((bh << 6) + t) << 2;

    float lsum = 0.f;
    for (int cc = 0; cc < nch; ++cc)
        lsum += Lpart[(slot0 + cc) * 64 + row];
    const float inv = 1.f / lsum;

    float ov[16] = {};
    for (int cc = 0; cc < nch; ++cc) {
        const unsigned short* p = Opart + (slot0 + cc) * 4096 + (row << 6) + cg;
#pragma unroll
        for (int j = 0; j < 16; ++j) ov[j] += bf2f(p[j]);
    }
    unsigned short outv[16];
#pragma unroll
    for (int j = 0; j < 16; ++j) outv[j] = f2bf(ov[j] * inv);

    unsigned short* dst = o + ((size_t)bh * T_SEQ + (r + m * P)) * HD + cg;
    *(int4*)dst       = *(const int4*)&outv[0];
    *(int4*)(dst + 8) = *(const int4*)&outv[8];
}

// ---------------------------------------------------------------------------
// Kernel 3: out projection, bf16 MFMA, global_load_lds staging.
// Tile 64x128, grid (128,4) = 512 blocks -> 2 blocks/CU.
// ---------------------------------------------------------------------------
__global__ __launch_bounds__(256) void out_gemm_mfma(
    const unsigned short* __restrict__ A,
    const unsigned short* __restrict__ W,   // 512 x 512 bf16
    const float* __restrict__ bias,
    float* __restrict__ out)
{
    __shared__ unsigned short As[64 * 64];    // 8 KB
    __shared__ unsigned short Bs[128 * 64];   // 16 KB

    const int tid  = threadIdx.x;
    const int wave = tid >> 6, lane = tid & 63;
    const int quad = lane >> 4, l15 = lane & 15;
    const int wm   = wave >> 1, wn = wave & 1;   // 2x2 wave grid: 32-row x 64-col
    const int row0 = blockIdx.x * 64;
    const int col0 = blockIdx.y * 128;
    const int lr8  = lane >> 3;
    const int sc   = lane & 7;

    floatx4 acc[2][4] = {};

    for (int k0 = 0; k0 < D_MODEL; k0 += 64) {
        const int h = k0 >> 6;
#pragma unroll
        for (int i = 0; i < 4; ++i) {          // B: 128 rows of W
            const int rb  = (wave << 5) + (i << 3);
            const int r   = rb + lr8;
            const int csw = sc ^ (r & 7);
            gload16(W + (size_t)(col0 + r) * D_MODEL + k0 + (csw << 3),
                    Bs + (rb << 6));
        }
#pragma unroll
        for (int i = 0; i < 2; ++i) {          // A: 64 rows, head-major gather
            const int rb  = (wave << 4) + (i << 3);
            const int r   = rb + lr8;
            const int csw = sc ^ (r & 7);
            const int rg = row0 + r;
            const int b = rg >> 11, t = rg & 2047;
            gload16(A + ((((size_t)b << 3) + h) * T_SEQ + t) * HD + (csw << 3),
                    As + (rb << 6));
        }
        __syncthreads();

#pragma unroll
        for (int ks = 0; ks < 2; ++ks) {
            short8 af[2], bfr[4];
            const int ch = (ks << 2) + quad;
#pragma unroll
            for (int mt = 0; mt < 2; ++mt) {
                const int row = (wm << 5) + (mt << 4) + l15;
                af[mt] = *(const short8*)(As + (row << 6) + ((ch ^ (row & 7)) << 3));
            }
#pragma unroll
            for (int nt = 0; nt < 4; ++nt) {
                const int col = (wn << 6) + (nt << 4) + l15;
                bfr[nt] = *(const short8*)(Bs + (col << 6) + ((ch ^ (col & 7)) << 3));
            }
#pragma unroll
            for (int mt = 0; mt < 2; ++mt)
#pragma unroll
                for (int nt = 0; nt < 4; ++nt)
                    acc[mt][nt] = __builtin_amdgcn_mfma_f32_16x16x32_bf16(
                        af[mt], bfr[nt], acc[mt][nt], 0, 0, 0);
        }
        __syncthreads();
    }

#pragma unroll
    for (int nt = 0; nt < 4; ++nt) {
        const int n = col0 + (wn << 6) + (nt << 4) + l15;
        const float bn = bias[n];
#pragma unroll
        for (int mt = 0; mt < 2; ++mt) {
#pragma unroll
            for (int reg = 0; reg < 4; ++reg) {
                const int m = row0 + (wm << 5) + (mt << 4) + (quad << 2) + reg;
                out[(size_t)m * D_MODEL + n] = acc[mt][nt][reg] + bn;
            }
        }
    }
}

// ---------------------------------------------------------------------------
extern "C" void kernel_launch(void* const* d_in, const int* in_sizes, int n_in,
                              void* d_out, int out_size, void* d_ws, size_t ws_size,
                              hipStream_t stream)
{
    const float* x        = (const float*)d_in[0];
    const int*   periods  = (const int*)  d_in[1];
    const float* in_w     = (const float*)d_in[2];
    const float* in_b     = (const float*)d_in[3];
    const float* out_w    = (const float*)d_in[4];
    const float* out_b    = (const float*)d_in[5];
    float*       out      = (float*)d_out;

    const size_t TENS = (size_t)BATCH * NHEAD * T_SEQ * HD;   // 4,194,304
    unsigned short* qb    = (unsigned short*)d_ws;
    unsigned short* kb    = qb + TENS;
    unsigned short* vb    = kb + TENS;
    unsigned short* aob   = vb + TENS;
    unsigned short* Opart = aob + TENS;                // 8192 slots x 4096 bf16
    float*          Lpart = (float*)(Opart + (size_t)8192 * 4096);
    unsigned short* Xb    = (unsigned short*)(Lpart + (size_t)8192 * 64);
    unsigned short* W1b   = Xb + (size_t)M_ROWS * D_MODEL;          // 1536x512
    unsigned short* W2b   = W1b + (size_t)3 * D_MODEL * D_MODEL;    // 512x512
    int*            items = (int*)(W2b + (size_t)D_MODEL * D_MODEL); // 2560 ints
    // ws usage: 4*8MB + 64MB + 2MB + 8+1.5+0.5MB + 10KB ~= 108 MiB

    // 0) fp32 -> bf16 conversion of X, in_proj_w, out_w + fused item build
    cvt_inputs<<<CVT_GROUPS / 256, 256, 0, stream>>>(x, in_w, out_w,
                                                     Xb, W1b, W2b,
                                                     periods, items);

    // 1) QKV projection (bf16 MFMA, async-staged), XCD-swizzled flat grid
    qkv_gemm_mfma<<<(M_ROWS / 128) * ((3 * D_MODEL) / 128), 256, 0, stream>>>(
        Xb, W1b, in_b, qb, kb, vb);

    // 2) flash attention over the dense item list (per-head contiguous ->
    //    XCD-spread; swapped-QK in-register softmax)
    attn_rc_mfma<<<MAX_ITEMS, 256, 0, stream>>>(qb, kb, vb, periods, aob,
                                                Opart, Lpart, items);
    // 2b) merge chunks (slots with mt >= 8)
    reduce_rc<<<dim3(64, BATCH * NHEAD), 256, 0, stream>>>(
        periods, Opart, Lpart, aob);

    // 3) out projection (bf16 MFMA, bf16 weights), 64x128 tiles, 2 blocks/CU
    dim3 g3(M_ROWS / 64, D_MODEL / 128);          // 128 x 4
    out_gemm_mfma<<<g3, 256, 0, stream>>>(aob, W2b, out_b, out);
}